// Round 14
// baseline (831.754 us; speedup 1.0000x reference)
//
#include <hip/hip_runtime.h>
#include <hip/hip_bf16.h>

// ---------------------------------------------------------------------------
// GAT (2 GATConv + 5-layer MLP), MI355X.
// R4: bf16 hi/lo planes end-to-end, split-bf16 MFMA (3 terms), fused el/er.
// R13: head-minor GAT output; agg = one wave per node, 768B wave-uniform
//     dwordx3 gather, zero barriers.
// R14: degree-balanced agg scheduling — counting-sort perm (descending
//     degree), built inside existing CSR kernels + 1 tiny dscan launch.
// ---------------------------------------------------------------------------

typedef __attribute__((ext_vector_type(8))) short short8;   // 8 bf16 = 4 VGPR
typedef __attribute__((ext_vector_type(4))) float float4v;  // MFMA C/D

__device__ inline short f2bf(float x) {
    union { float f; unsigned u; } v; v.f = x;
    unsigned r = v.u + 0x7FFFu + ((v.u >> 16) & 1u);   // RNE
    return (short)(r >> 16);
}
__device__ inline float bf2f(short b) {
    union { float f; unsigned u; } v;
    v.u = ((unsigned)(unsigned short)b) << 16;
    return v.f;
}
__device__ inline float bfhi(unsigned u) {
    union { unsigned u; float f; } v; v.u = u & 0xffff0000u; return v.f;
}
__device__ inline float bflo(unsigned u) {
    union { unsigned u; float f; } v; v.u = u << 16; return v.f;
}
__device__ inline short8 zero8() { short8 z = {0,0,0,0,0,0,0,0}; return z; }

#define BM 128
#define BN 128
#define BK 32
#define LSTR 40    // LDS row stride in shorts (80 B, 16B-aligned, breaks pow2)
#define MSTR 136   // act row stride in shorts (272 B = 17x16B, breaks pow2)
#define MROWS 64   // mlp_fused rows per block (55 KB LDS -> 2 blocks/CU)

// ---------------------------------------------------------------------------
// Fused prep: [0, cb) conv_split | [cb, cb+wb) weight transpose | rest hist.
__global__ void prep_kernel(
    const float* __restrict__ in_feat, short* __restrict__ P1h,
    short* __restrict__ P1l, int n4, int cb, int wb,
    const int* __restrict__ dst, int* __restrict__ cnt, int E,
    const float* __restrict__ w1, const float* __restrict__ w2,
    const float* __restrict__ m1, const float* __restrict__ m2,
    const float* __restrict__ m3, const float* __restrict__ m4,
    const float* __restrict__ w5,
    short* __restrict__ w1h, short* __restrict__ w1l,
    short* __restrict__ w2h, short* __restrict__ w2l,
    short* __restrict__ m1h, short* __restrict__ m1l,
    short* __restrict__ m2h, short* __restrict__ m2l,
    short* __restrict__ m3h, short* __restrict__ m3l,
    short* __restrict__ m4h, short* __restrict__ m4l,
    short* __restrict__ w5h, short* __restrict__ w5l)
{
    int blk = blockIdx.x;
    if (blk < cb) {
        int i = blk * 256 + threadIdx.x;
        if (i >= n4) return;
        float4 v = *(const float4*)(in_feat + (size_t)i * 4);
        float xs[4] = {v.x, v.y, v.z, v.w};
        short hs[4], ls[4];
        #pragma unroll
        for (int j = 0; j < 4; ++j) {
            hs[j] = f2bf(xs[j]);
            ls[j] = f2bf(xs[j] - bf2f(hs[j]));
        }
        *(uint2*)(P1h + (size_t)i * 4) = *(uint2*)hs;
        *(uint2*)(P1l + (size_t)i * 4) = *(uint2*)ls;
    } else if (blk < cb + wb) {
        int j = (blk - cb) * 256 + threadIdx.x;
        const float* src; short* th; short* tl; int Nc, base;
        if      (j < 49152)  { src = w1; th = w1h; tl = w1l; Nc = 384; base = 0; }
        else if (j < 98304)  { src = w2; th = w2h; tl = w2l; Nc = 384; base = 49152; }
        else if (j < 114688) { src = m1; th = m1h; tl = m1l; Nc = 128; base = 98304; }
        else if (j < 131072) { src = m2; th = m2h; tl = m2l; Nc = 128; base = 114688; }
        else if (j < 147456) { src = m3; th = m3h; tl = m3l; Nc = 128; base = 131072; }
        else if (j < 163840) { src = m4; th = m4h; tl = m4l; Nc = 128; base = 147456; }
        else if (j < 164608) { src = w5; th = w5h; tl = w5l; Nc = 6;   base = 163840; }
        else return;
        int i = j - base;
        int k = i / Nc, c = i - k * Nc;
        float v = src[i];
        short h = f2bf(v);
        th[(size_t)c * 128 + k] = h;
        tl[(size_t)c * 128 + k] = f2bf(v - bf2f(h));
    } else {
        int e = (blk - cb - wb) * 256 + threadIdx.x;
        if (e < E) atomicAdd(&cnt[dst[e]], 1);
    }
}

// ---------------------------------------------------------------------------
// GEMM (GAT layers): flags: 1 bias, 2 lrelu, 4 el/er, 8 fp32 C, 16 hi plane,
// 32 lo plane, 64 head-minor hi plane [(r*128+(c-colBase))*3 + head].
__global__ __launch_bounds__(256) void gemm_mfma(
    const short* __restrict__ Ahi, const short* __restrict__ Alo,
    const short* __restrict__ Bth, const short* __restrict__ Btl,
    const float* __restrict__ bias,
    float* __restrict__ Cf, short* __restrict__ Chi, short* __restrict__ Clo,
    float* __restrict__ el, float* __restrict__ er,
    const float* __restrict__ al, const float* __restrict__ ar,
    int M, int Nc, int flags)
{
    __shared__ short Ah[BM * LSTR], Al_[BM * LSTR];
    __shared__ short Bh[BN * LSTR], Bl_[BN * LSTR];

    int tid = threadIdx.x, lane = tid & 63, wave = tid >> 6;
    int l15 = lane & 15, q = lane >> 4;
    int rowBase = blockIdx.y * BM, colBase = blockIdx.x * BN;

    float4v acc[2][8];
    #pragma unroll
    for (int mt = 0; mt < 2; ++mt)
        #pragma unroll
        for (int nt = 0; nt < 8; ++nt)
            acc[mt][nt] = (float4v){0.f, 0.f, 0.f, 0.f};

    for (int k0 = 0; k0 < 128; k0 += BK) {
        #pragma unroll
        for (int s = 0; s < 2; ++s) {
            int c = tid + s * 256;
            int r = c >> 2, kq = (c & 3) * 8;
            int gr = rowBase + r;
            short8 vh = zero8(), vl = zero8();
            if (gr < M) {
                vh = *(const short8*)(Ahi + (size_t)gr * 128 + k0 + kq);
                vl = *(const short8*)(Alo + (size_t)gr * 128 + k0 + kq);
            }
            *(short8*)&Ah[r * LSTR + kq]  = vh;
            *(short8*)&Al_[r * LSTR + kq] = vl;
            int gc = colBase + r;
            short8 wh = zero8(), wl = zero8();
            if (gc < Nc) {
                wh = *(const short8*)(Bth + (size_t)gc * 128 + k0 + kq);
                wl = *(const short8*)(Btl + (size_t)gc * 128 + k0 + kq);
            }
            *(short8*)&Bh[r * LSTR + kq]  = wh;
            *(short8*)&Bl_[r * LSTR + kq] = wl;
        }
        __syncthreads();

        short8 aH[2], aL2[2];
        #pragma unroll
        for (int mt = 0; mt < 2; ++mt) {
            int off = (wave * 32 + mt * 16 + l15) * LSTR + q * 8;
            aH[mt]  = *(short8*)&Ah[off];
            aL2[mt] = *(short8*)&Al_[off];
        }
        #pragma unroll
        for (int nt = 0; nt < 8; ++nt) {
            int off = (nt * 16 + l15) * LSTR + q * 8;
            short8 bH = *(short8*)&Bh[off];
            short8 bL = *(short8*)&Bl_[off];
            #pragma unroll
            for (int mt = 0; mt < 2; ++mt) {
                acc[mt][nt] = __builtin_amdgcn_mfma_f32_16x16x32_bf16(aH[mt], bH, acc[mt][nt], 0, 0, 0);
                acc[mt][nt] = __builtin_amdgcn_mfma_f32_16x16x32_bf16(aH[mt], bL, acc[mt][nt], 0, 0, 0);
                acc[mt][nt] = __builtin_amdgcn_mfma_f32_16x16x32_bf16(aL2[mt], bH, acc[mt][nt], 0, 0, 0);
            }
        }
        __syncthreads();
    }

    if (flags & 4) {
        const float* alh = al + colBase;
        const float* arh = ar + colBase;
        float pel[2][4] = {}, per_[2][4] = {};
        #pragma unroll
        for (int nt = 0; nt < 8; ++nt) {
            float av = alh[nt * 16 + l15];
            float rv = arh[nt * 16 + l15];
            #pragma unroll
            for (int mt = 0; mt < 2; ++mt)
                #pragma unroll
                for (int i = 0; i < 4; ++i) {
                    pel[mt][i]  += acc[mt][nt][i] * av;
                    per_[mt][i] += acc[mt][nt][i] * rv;
                }
        }
        #pragma unroll
        for (int mask = 1; mask < 16; mask <<= 1)
            #pragma unroll
            for (int mt = 0; mt < 2; ++mt)
                #pragma unroll
                for (int i = 0; i < 4; ++i) {
                    pel[mt][i]  += __shfl_xor(pel[mt][i], mask);
                    per_[mt][i] += __shfl_xor(per_[mt][i], mask);
                }
        if (l15 == 0) {
            #pragma unroll
            for (int mt = 0; mt < 2; ++mt)
                #pragma unroll
                for (int i = 0; i < 4; ++i) {
                    int r = rowBase + wave * 32 + mt * 16 + q * 4 + i;
                    if (r < M) {
                        el[r * 3 + blockIdx.x] = pel[mt][i];
                        er[r * 3 + blockIdx.x] = per_[mt][i];
                    }
                }
        }
    }

    #pragma unroll
    for (int mt = 0; mt < 2; ++mt) {
        #pragma unroll
        for (int nt = 0; nt < 8; ++nt) {
            int c = colBase + nt * 16 + l15;
            if (c >= Nc) continue;
            float bv = (flags & 1) ? bias[c] : 0.f;
            #pragma unroll
            for (int i = 0; i < 4; ++i) {
                int r = rowBase + wave * 32 + mt * 16 + q * 4 + i;
                if (r >= M) continue;
                float v = acc[mt][nt][i] + bv;
                if (flags & 2) v = (v < 0.f) ? 0.01f * v : v;
                if (flags & 8)  Cf[(size_t)r * Nc + c] = v;
                if (flags & 16) {
                    size_t idx = (flags & 64)
                        ? ((size_t)r * 128 + (size_t)(c - colBase)) * 3 + blockIdx.x
                        : (size_t)r * Nc + c;
                    short hh = f2bf(v);
                    Chi[idx] = hh;
                    if (flags & 32) Clo[idx] = f2bf(v - bf2f(hh));
                }
            }
        }
    }
}

// ---------------------------------------------------------------------------
// Fused MLP head: 4x (128->128, bias, lrelu) + (128->6, bias) in one kernel.
__global__ __launch_bounds__(256) void mlp_fused(
    const short* __restrict__ Ph, const short* __restrict__ Pl,
    const short* __restrict__ w1h, const short* __restrict__ w1l,
    const short* __restrict__ w2h, const short* __restrict__ w2l,
    const short* __restrict__ w3h, const short* __restrict__ w3l,
    const short* __restrict__ w4h, const short* __restrict__ w4l,
    const short* __restrict__ w5h, const short* __restrict__ w5l,
    const float* __restrict__ b1, const float* __restrict__ b2,
    const float* __restrict__ b3, const float* __restrict__ b4,
    const float* __restrict__ b5,
    float* __restrict__ out, int M)
{
    __shared__ short AH[MROWS * MSTR], AL[MROWS * MSTR];
    __shared__ short WH[128 * LSTR], WL[128 * LSTR];

    int tid = threadIdx.x, lane = tid & 63, wave = tid >> 6;
    int l15 = lane & 15, q = lane >> 4;
    int rowBase = blockIdx.x * MROWS;

    #pragma unroll
    for (int s = 0; s < 4; ++s) {
        int idx = tid + s * 256;
        int r = idx >> 4, kq = (idx & 15) * 8;
        int gr = rowBase + r;
        short8 vh = zero8(), vl = zero8();
        if (gr < M) {
            vh = *(const short8*)(Ph + (size_t)gr * 128 + kq);
            vl = *(const short8*)(Pl + (size_t)gr * 128 + kq);
        }
        *(short8*)&AH[r * MSTR + kq] = vh;
        *(short8*)&AL[r * MSTR + kq] = vl;
    }

    const short* Whs[4] = {w1h, w2h, w3h, w4h};
    const short* Wls[4] = {w1l, w2l, w3l, w4l};
    const float* Bss[4] = {b1, b2, b3, b4};

    #pragma unroll
    for (int L = 0; L < 4; ++L) {
        float4v acc[8];
        #pragma unroll
        for (int nt = 0; nt < 8; ++nt)
            acc[nt] = (float4v){0.f, 0.f, 0.f, 0.f};

        for (int k0 = 0; k0 < 128; k0 += BK) {
            #pragma unroll
            for (int s = 0; s < 4; ++s) {
                int idx = tid + s * 256;
                int plane = idx >> 9, rem = idx & 511;
                int c = rem >> 2, kq = (rem & 3) * 8;
                short8 v = *(const short8*)((plane ? Wls[L] : Whs[L]) +
                                            (size_t)c * 128 + k0 + kq);
                *(short8*)&((plane ? WL : WH)[c * LSTR + kq]) = v;
            }
            __syncthreads();
            int offa = (wave * 16 + l15) * MSTR + k0 + q * 8;
            short8 aH  = *(short8*)&AH[offa];
            short8 aL2 = *(short8*)&AL[offa];
            #pragma unroll
            for (int nt = 0; nt < 8; ++nt) {
                int off = (nt * 16 + l15) * LSTR + q * 8;
                short8 bH = *(short8*)&WH[off];
                short8 bL = *(short8*)&WL[off];
                acc[nt] = __builtin_amdgcn_mfma_f32_16x16x32_bf16(aH, bH, acc[nt], 0, 0, 0);
                acc[nt] = __builtin_amdgcn_mfma_f32_16x16x32_bf16(aH, bL, acc[nt], 0, 0, 0);
                acc[nt] = __builtin_amdgcn_mfma_f32_16x16x32_bf16(aL2, bH, acc[nt], 0, 0, 0);
            }
            __syncthreads();
        }
        #pragma unroll
        for (int nt = 0; nt < 8; ++nt) {
            int c = nt * 16 + l15;
            float bv = Bss[L][c];
            #pragma unroll
            for (int i = 0; i < 4; ++i) {
                int r = wave * 16 + q * 4 + i;
                float v = acc[nt][i] + bv;
                v = (v < 0.f) ? 0.01f * v : v;
                short hh = f2bf(v);
                AH[r * MSTR + c] = hh;
                AL[r * MSTR + c] = f2bf(v - bf2f(hh));
            }
        }
        __syncthreads();
    }

    float4v acc5 = (float4v){0.f, 0.f, 0.f, 0.f};
    for (int k0 = 0; k0 < 128; k0 += BK) {
        if (tid < 128) {
            int plane = tid >> 6, rem = tid & 63;
            int c = rem >> 2, kq = (rem & 3) * 8;
            short8 v = zero8();
            if (c < 6)
                v = *(const short8*)((plane ? w5l : w5h) + (size_t)c * 128 + k0 + kq);
            *(short8*)&((plane ? WL : WH)[c * LSTR + kq]) = v;
        }
        __syncthreads();
        int offa = (wave * 16 + l15) * MSTR + k0 + q * 8;
        short8 aH  = *(short8*)&AH[offa];
        short8 aL2 = *(short8*)&AL[offa];
        int offb = l15 * LSTR + q * 8;
        short8 bH = *(short8*)&WH[offb];
        short8 bL = *(short8*)&WL[offb];
        acc5 = __builtin_amdgcn_mfma_f32_16x16x32_bf16(aH, bH, acc5, 0, 0, 0);
        acc5 = __builtin_amdgcn_mfma_f32_16x16x32_bf16(aH, bL, acc5, 0, 0, 0);
        acc5 = __builtin_amdgcn_mfma_f32_16x16x32_bf16(aL2, bH, acc5, 0, 0, 0);
        __syncthreads();
    }
    if (l15 < 6) {
        float bv = b5[l15];
        #pragma unroll
        for (int i = 0; i < 4; ++i) {
            int r = rowBase + wave * 16 + q * 4 + i;
            if (r < M) out[(size_t)r * 6 + l15] = acc5[i] + bv;
        }
    }
}

// ---------------------------------------------------------------------------
// CSR build (hist lives in prep_kernel)
__global__ __launch_bounds__(1024) void scan_block(const int* __restrict__ cnt,
                                                   int* __restrict__ off,
                                                   int* __restrict__ bsum, int n)
{
    __shared__ int tmp[1024];
    int tid = threadIdx.x;
    int i = blockIdx.x * 1024 + tid;
    int v = (i < n) ? cnt[i] : 0;
    tmp[tid] = v;
    __syncthreads();
    for (int s = 1; s < 1024; s <<= 1) {
        int t = (tid >= s) ? tmp[tid - s] : 0;
        __syncthreads();
        tmp[tid] += t;
        __syncthreads();
    }
    if (i < n) off[i] = tmp[tid] - v;
    if (tid == 1023) bsum[blockIdx.x] = tmp[1023];
}

// Adds chunk prefixes + builds degree histogram (cnt still holds degrees).
__global__ void scan_add2(int* __restrict__ off, const int* __restrict__ bsum,
                          const int* __restrict__ cnt, int* __restrict__ dhist,
                          int n, int nb)
{
    __shared__ int pre[64];
    int tid = threadIdx.x;
    if (tid < 64) {
        int v = (tid < nb) ? bsum[tid] : 0;
        #pragma unroll
        for (int s = 1; s < 64; s <<= 1) {
            int t = __shfl_up(v, s);
            if (tid >= s) v += t;
        }
        pre[tid] = v;
    }
    __syncthreads();
    int i = blockIdx.x * blockDim.x + tid;
    if (i < n) {
        int chunk = i >> 10;
        off[i] += chunk ? pre[chunk - 1] : 0;
        atomicAdd(&dhist[min(cnt[i], 255)], 1);
    }
    if (i == 0) off[n] = pre[nb - 1];
}

// Suffix-scan the 256 degree bins: dbase[bin] = #nodes with degree > bin
// (descending-degree dispatch: heavy nodes first, light tail).
__global__ __launch_bounds__(256) void dscan_kernel(const int* __restrict__ dhist,
                                                    int* __restrict__ dbase)
{
    __shared__ int tmp[256];
    int tid = threadIdx.x;
    tmp[tid] = dhist[255 - tid];
    __syncthreads();
    for (int s = 1; s < 256; s <<= 1) {
        int t = (tid >= s) ? tmp[tid - s] : 0;
        __syncthreads();
        tmp[tid] += t;
        __syncthreads();
    }
    int bin = 255 - tid;
    dbase[bin] = tmp[tid] - dhist[bin];
}

// scatter: blocks < eb sort edges (consume cnt via atomicSub);
// blocks >= eb scatter node ids into perm by degree bin (uses stable off[]).
__global__ void scatter_kernel(const int* __restrict__ src, const int* __restrict__ dst,
                               const int* __restrict__ off, int* __restrict__ cnt,
                               int* __restrict__ csrc, int E, int eb,
                               int* __restrict__ dbase, int* __restrict__ perm, int N)
{
    int blk = blockIdx.x;
    if (blk < eb) {
        int e = blk * 256 + threadIdx.x;
        if (e < E) {
            int d = dst[e];
            int p = atomicSub(&cnt[d], 1) - 1;
            csrc[off[d] + p] = src[e];
        }
    } else {
        int i = (blk - eb) * 256 + threadIdx.x;
        if (i < N) {
            int deg = off[i + 1] - off[i];
            int pos = atomicAdd(&dbase[min(deg, 255)], 1);
            perm[pos] = i;
        }
    }
}

// ---------------------------------------------------------------------------
// Fused edge-softmax + weighted gather + bias + lrelu + head-mean.
// ONE wave per node (4 equal-degree nodes / block via perm), zero barriers.
// h is head-minor [n][128f][3h] bf16-hi; per edge one wave-uniform 768B load.
__global__ __launch_bounds__(256) void agg_kernel(
    const short* __restrict__ h, const float* __restrict__ el,
    const float* __restrict__ er, const int* __restrict__ off,
    const int* __restrict__ csrc, const int* __restrict__ perm,
    const float* __restrict__ bias,
    short* __restrict__ outH, short* __restrict__ outL, int N)
{
    int w = threadIdx.x >> 6;      // wave slot 0..3
    int l = threadIdx.x & 63;
    int idx = blockIdx.x * 4 + w;
    if (idx >= N) return;
    int n = perm[idx];

    __shared__ int   ssrc[4][64];        // wave-private
    __shared__ float sw3[4][64][3];      // wave-private, [edge][head]

    int beg = off[n], end = off[n + 1];
    int deg = end - beg;
    float er0 = er[n * 3 + 0], er1 = er[n * 3 + 1], er2 = er[n * 3 + 2];

    float a00 = 0.f, a01 = 0.f, a02 = 0.f;
    float a10 = 0.f, a11 = 0.f, a12 = 0.f;
    float den0 = 0.f, den1 = 0.f, den2 = 0.f;
    float m0 = -1e30f, m1 = -1e30f, m2 = -1e30f;

    for (int base = 0; base < deg; base += 64) {
        int cnt = min(64, deg - base);
        if (l < cnt) ssrc[w][l] = csrc[beg + base + l];
        float e0 = -1e30f, e1 = -1e30f, e2 = -1e30f;
        if (l < cnt) {
            const float* ep = el + (size_t)ssrc[w][l] * 3;
            float t0 = ep[0] + er0, t1 = ep[1] + er1, t2 = ep[2] + er2;
            e0 = (t0 < 0.f) ? 0.2f * t0 : t0;
            e1 = (t1 < 0.f) ? 0.2f * t1 : t1;
            e2 = (t2 < 0.f) ? 0.2f * t2 : t2;
        }
        float c0 = e0, c1 = e1, c2 = e2;
        #pragma unroll
        for (int msk = 1; msk < 64; msk <<= 1) {
            c0 = fmaxf(c0, __shfl_xor(c0, msk));
            c1 = fmaxf(c1, __shfl_xor(c1, msk));
            c2 = fmaxf(c2, __shfl_xor(c2, msk));
        }
        float n0 = fmaxf(m0, c0), n1 = fmaxf(m1, c1), n2 = fmaxf(m2, c2);
        float s0 = __expf(m0 - n0), s1 = __expf(m1 - n1), s2 = __expf(m2 - n2);
        a00 *= s0; a01 *= s1; a02 *= s2;
        a10 *= s0; a11 *= s1; a12 *= s2;
        den0 *= s0; den1 *= s1; den2 *= s2;
        float w0 = (l < cnt) ? __expf(e0 - n0) : 0.f;
        float w1 = (l < cnt) ? __expf(e1 - n1) : 0.f;
        float w2 = (l < cnt) ? __expf(e2 - n2) : 0.f;
        float ws0 = w0, ws1 = w1, ws2 = w2;
        #pragma unroll
        for (int msk = 1; msk < 64; msk <<= 1) {
            ws0 += __shfl_xor(ws0, msk);
            ws1 += __shfl_xor(ws1, msk);
            ws2 += __shfl_xor(ws2, msk);
        }
        den0 += ws0; den1 += ws1; den2 += ws2;
        sw3[w][l][0] = w0; sw3[w][l][1] = w1; sw3[w][l][2] = w2;
        m0 = n0; m1 = n1; m2 = n2;
        #pragma unroll 4
        for (int qq = 0; qq < cnt; ++qq) {
            int s = ssrc[w][qq];
            float q0 = sw3[w][qq][0], q1 = sw3[w][qq][1], q2 = sw3[w][qq][2];
            uint3 v = *(const uint3*)(h + (size_t)s * 384 + l * 6);
            a00 += q0 * bflo(v.x); a01 += q1 * bfhi(v.x); a02 += q2 * bflo(v.y);
            a10 += q0 * bfhi(v.y); a11 += q1 * bflo(v.z); a12 += q2 * bfhi(v.z);
        }
    }
    float r0 = 1.f / (den0 + 1e-9f), r1 = 1.f / (den1 + 1e-9f), r2 = 1.f / (den2 + 1e-9f);
    if (deg == 0) { r0 = r1 = r2 = 0.f; }
    int f0 = 2 * l, f1 = 2 * l + 1;
    float b00 = bias[f0], b01 = bias[128 + f0], b02 = bias[256 + f0];
    float b10 = bias[f1], b11 = bias[128 + f1], b12 = bias[256 + f1];
    float v00 = a00 * r0 + b00; v00 = (v00 < 0.f) ? 0.01f * v00 : v00;
    float v01 = a01 * r1 + b01; v01 = (v01 < 0.f) ? 0.01f * v01 : v01;
    float v02 = a02 * r2 + b02; v02 = (v02 < 0.f) ? 0.01f * v02 : v02;
    float v10 = a10 * r0 + b10; v10 = (v10 < 0.f) ? 0.01f * v10 : v10;
    float v11 = a11 * r1 + b11; v11 = (v11 < 0.f) ? 0.01f * v11 : v11;
    float v12 = a12 * r2 + b12; v12 = (v12 < 0.f) ? 0.01f * v12 : v12;
    float mx = (v00 + v01 + v02) * (1.0f / 3.0f);
    float my = (v10 + v11 + v12) * (1.0f / 3.0f);
    short hx = f2bf(mx), lx = f2bf(mx - bf2f(hx));
    short hy = f2bf(my), ly = f2bf(my - bf2f(hy));
    unsigned ph = (unsigned)(unsigned short)hx | ((unsigned)(unsigned short)hy << 16);
    unsigned pl = (unsigned)(unsigned short)lx | ((unsigned)(unsigned short)ly << 16);
    *(unsigned*)(outH + (size_t)n * 128 + f0) = ph;
    *(unsigned*)(outL + (size_t)n * 128 + f0) = pl;
}

// ---------------------------------------------------------------------------
extern "C" void kernel_launch(void* const* d_in, const int* in_sizes, int n_in,
                              void* d_out, int out_size, void* d_ws, size_t ws_size,
                              hipStream_t stream)
{
    const float* in_feat = (const float*)d_in[0];
    const int*   src     = (const int*)d_in[1];
    const int*   dst     = (const int*)d_in[2];
    const float* W1  = (const float*)d_in[3];
    const float* al1 = (const float*)d_in[4];
    const float* ar1 = (const float*)d_in[5];
    const float* b1  = (const float*)d_in[6];
    const float* W2  = (const float*)d_in[7];
    const float* al2 = (const float*)d_in[8];
    const float* ar2 = (const float*)d_in[9];
    const float* b2  = (const float*)d_in[10];
    const float* lw1 = (const float*)d_in[11];
    const float* lb1 = (const float*)d_in[12];
    const float* lw2 = (const float*)d_in[13];
    const float* lb2 = (const float*)d_in[14];
    const float* lw3 = (const float*)d_in[15];
    const float* lb3 = (const float*)d_in[16];
    const float* lw4 = (const float*)d_in[17];
    const float* lb4 = (const float*)d_in[18];
    const float* lw5 = (const float*)d_in[19];
    const float* lb5 = (const float*)d_in[20];

    const int N = in_sizes[0] / 128;   // 50000
    const int E = in_sizes[1];         // 800000

    size_t o = 0;
    auto alloc = [&](size_t bytes) { size_t p = o; o = (o + bytes + 255) & ~(size_t)255; return p; };
    char* ws = (char*)d_ws;
    short* P1h = (short*)(ws + alloc((size_t)N * 128 * 2));
    short* P1l = (short*)(ws + alloc((size_t)N * 128 * 2));
    short* P2h = (short*)(ws + alloc((size_t)N * 128 * 2));
    short* P2l = (short*)(ws + alloc((size_t)N * 128 * 2));
    short* AbH = (short*)(ws + alloc((size_t)N * 384 * 2));   // GAT out, hi, head-minor
    float* el  = (float*)(ws + alloc((size_t)N * 3 * 4));
    float* er  = (float*)(ws + alloc((size_t)N * 3 * 4));
    int*   cnt   = (int*)(ws + alloc((size_t)N * 4));
    int*   dhist = (int*)(ws + alloc((size_t)256 * 4));       // adjacent to cnt
    int*   dbase = (int*)(ws + alloc((size_t)256 * 4));
    int*   perm  = (int*)(ws + alloc((size_t)N * 4));
    int*   off  = (int*)(ws + alloc((size_t)(N + 1) * 4));
    int*   bsum = (int*)(ws + alloc((size_t)4096));
    int*   csrc = (int*)(ws + alloc((size_t)E * 4));
    short* w1th = (short*)(ws + alloc((size_t)384 * 128 * 2));
    short* w1tl = (short*)(ws + alloc((size_t)384 * 128 * 2));
    short* w2th = (short*)(ws + alloc((size_t)384 * 128 * 2));
    short* w2tl = (short*)(ws + alloc((size_t)384 * 128 * 2));
    short* l1th = (short*)(ws + alloc((size_t)128 * 128 * 2));
    short* l1tl = (short*)(ws + alloc((size_t)128 * 128 * 2));
    short* l2th = (short*)(ws + alloc((size_t)128 * 128 * 2));
    short* l2tl = (short*)(ws + alloc((size_t)128 * 128 * 2));
    short* l3th = (short*)(ws + alloc((size_t)128 * 128 * 2));
    short* l3tl = (short*)(ws + alloc((size_t)128 * 128 * 2));
    short* l4th = (short*)(ws + alloc((size_t)128 * 128 * 2));
    short* l4tl = (short*)(ws + alloc((size_t)128 * 128 * 2));
    short* l5th = (short*)(ws + alloc((size_t)6 * 128 * 2));
    short* l5tl = (short*)(ws + alloc((size_t)6 * 128 * 2));
    (void)ws_size;

    float* out = (float*)d_out;

    // ---- fused prep (one memset covers cnt + dhist, they are adjacent)
    hipMemsetAsync(cnt, 0, (size_t)((char*)(dhist + 256) - (char*)cnt), stream);
    int n4 = N * 128 / 4;
    int cb = (n4 + 255) / 256;
    int wb = (164608 + 255) / 256;
    int hb = (E + 255) / 256;
    prep_kernel<<<cb + wb + hb, 256, 0, stream>>>(
        in_feat, P1h, P1l, n4, cb, wb, dst, cnt, E,
        W1, W2, lw1, lw2, lw3, lw4, lw5,
        w1th, w1tl, w2th, w2tl, l1th, l1tl, l2th, l2tl,
        l3th, l3tl, l4th, l4tl, l5th, l5tl);

    // ---- CSR scan + degree histogram + perm + scatter
    int nb = (N + 1023) / 1024;
    scan_block<<<nb, 1024, 0, stream>>>(cnt, off, bsum, N);
    scan_add2<<<(N + 255) / 256, 256, 0, stream>>>(off, bsum, cnt, dhist, N, nb);
    dscan_kernel<<<1, 256, 0, stream>>>(dhist, dbase);
    int eb = (E + 255) / 256;
    int pb = (N + 255) / 256;
    scatter_kernel<<<eb + pb, 256, 0, stream>>>(src, dst, off, cnt, csrc, E, eb,
                                                dbase, perm, N);

    int RB = (N + BM - 1) / BM;
    auto gemm = [&](const short* ah, const short* alo, const short* bth, const short* btl,
                    const float* bias, float* cf, short* chi, short* clo,
                    float* elp, float* erp, const float* alp, const float* arp,
                    int Nc, int flags) {
        dim3 grid((Nc + BN - 1) / BN, RB);
        gemm_mfma<<<grid, 256, 0, stream>>>(ah, alo, bth, btl, bias, cf, chi, clo,
                                            elp, erp, alp, arp, N, Nc, flags);
    };
    int aggGrid = (N + 3) / 4;

    // ---- GAT layer 1
    gemm(P1h, P1l, w1th, w1tl, nullptr, nullptr, AbH, nullptr, el, er, al1, ar1, 384, 4 | 16 | 64);
    agg_kernel<<<aggGrid, 256, 0, stream>>>(AbH, el, er, off, csrc, perm, b1, P2h, P2l, N);

    // ---- GAT layer 2
    gemm(P2h, P2l, w2th, w2tl, nullptr, nullptr, AbH, nullptr, el, er, al2, ar2, 384, 4 | 16 | 64);
    agg_kernel<<<aggGrid, 256, 0, stream>>>(AbH, el, er, off, csrc, perm, b2, P1h, P1l, N);

    // ---- MLP head (fused lin1..lin5, 64-node blocks)
    int RBM = (N + MROWS - 1) / MROWS;
    mlp_fused<<<RBM, 256, 0, stream>>>(P1h, P1l,
                                       l1th, l1tl, l2th, l2tl, l3th, l3tl,
                                       l4th, l4tl, l5th, l5tl,
                                       lb1, lb2, lb3, lb4, lb5, out, N);
}

// Round 15
// 565.970 us; speedup vs baseline: 1.4696x; 1.4696x over previous
//
#include <hip/hip_runtime.h>
#include <hip/hip_bf16.h>

// ---------------------------------------------------------------------------
// GAT (2 GATConv + 5-layer MLP), MI355X.
// R4: bf16 hi/lo planes end-to-end, split-bf16 MFMA (3 terms), fused el/er.
// R9 (proven): agg block-per-node (3 waves = 3 heads), in-kernel online
//     softmax, wave-uniform 256B row gather (R10's edge-split regressed).
// R10: mlp_fused 64-node blocks. R12: prep_kernel fuses conv+convw+hist;
//     scan_tops folded into scan_add2; scatter reuses cnt via atomicSub.
// R15: revert of R13/R14 (head-minor agg + degree-balance both failed their
//     predictions; agg is request-rate-bound at ~6.1 TB/s delivered).
// ---------------------------------------------------------------------------

typedef __attribute__((ext_vector_type(8))) short short8;   // 8 bf16 = 4 VGPR
typedef __attribute__((ext_vector_type(4))) float float4v;  // MFMA C/D

__device__ inline short f2bf(float x) {
    union { float f; unsigned u; } v; v.f = x;
    unsigned r = v.u + 0x7FFFu + ((v.u >> 16) & 1u);   // RNE
    return (short)(r >> 16);
}
__device__ inline float bf2f(short b) {
    union { float f; unsigned u; } v;
    v.u = ((unsigned)(unsigned short)b) << 16;
    return v.f;
}
__device__ inline short8 zero8() { short8 z = {0,0,0,0,0,0,0,0}; return z; }

#define BM 128
#define BN 128
#define BK 32
#define LSTR 40    // LDS row stride in shorts (80 B, 16B-aligned, breaks pow2)
#define MSTR 136   // act row stride in shorts (272 B = 17x16B, breaks pow2)
#define MROWS 64   // mlp_fused rows per block (55 KB LDS -> 2 blocks/CU)

// ---------------------------------------------------------------------------
// Fused prep: [0, cb) conv_split | [cb, cb+wb) weight transpose | rest hist.
__global__ void prep_kernel(
    const float* __restrict__ in_feat, short* __restrict__ P1h,
    short* __restrict__ P1l, int n4, int cb, int wb,
    const int* __restrict__ dst, int* __restrict__ cnt, int E,
    const float* __restrict__ w1, const float* __restrict__ w2,
    const float* __restrict__ m1, const float* __restrict__ m2,
    const float* __restrict__ m3, const float* __restrict__ m4,
    const float* __restrict__ w5,
    short* __restrict__ w1h, short* __restrict__ w1l,
    short* __restrict__ w2h, short* __restrict__ w2l,
    short* __restrict__ m1h, short* __restrict__ m1l,
    short* __restrict__ m2h, short* __restrict__ m2l,
    short* __restrict__ m3h, short* __restrict__ m3l,
    short* __restrict__ m4h, short* __restrict__ m4l,
    short* __restrict__ w5h, short* __restrict__ w5l)
{
    int blk = blockIdx.x;
    if (blk < cb) {
        int i = blk * 256 + threadIdx.x;
        if (i >= n4) return;
        float4 v = *(const float4*)(in_feat + (size_t)i * 4);
        float xs[4] = {v.x, v.y, v.z, v.w};
        short hs[4], ls[4];
        #pragma unroll
        for (int j = 0; j < 4; ++j) {
            hs[j] = f2bf(xs[j]);
            ls[j] = f2bf(xs[j] - bf2f(hs[j]));
        }
        *(uint2*)(P1h + (size_t)i * 4) = *(uint2*)hs;
        *(uint2*)(P1l + (size_t)i * 4) = *(uint2*)ls;
    } else if (blk < cb + wb) {
        int j = (blk - cb) * 256 + threadIdx.x;
        const float* src; short* th; short* tl; int Nc, base;
        if      (j < 49152)  { src = w1; th = w1h; tl = w1l; Nc = 384; base = 0; }
        else if (j < 98304)  { src = w2; th = w2h; tl = w2l; Nc = 384; base = 49152; }
        else if (j < 114688) { src = m1; th = m1h; tl = m1l; Nc = 128; base = 98304; }
        else if (j < 131072) { src = m2; th = m2h; tl = m2l; Nc = 128; base = 114688; }
        else if (j < 147456) { src = m3; th = m3h; tl = m3l; Nc = 128; base = 131072; }
        else if (j < 163840) { src = m4; th = m4h; tl = m4l; Nc = 128; base = 147456; }
        else if (j < 164608) { src = w5; th = w5h; tl = w5l; Nc = 6;   base = 163840; }
        else return;
        int i = j - base;
        int k = i / Nc, c = i - k * Nc;
        float v = src[i];
        short h = f2bf(v);
        th[(size_t)c * 128 + k] = h;
        tl[(size_t)c * 128 + k] = f2bf(v - bf2f(h));
    } else {
        int e = (blk - cb - wb) * 256 + threadIdx.x;
        if (e < E) atomicAdd(&cnt[dst[e]], 1);
    }
}

// ---------------------------------------------------------------------------
// GEMM (GAT layers): C[M x Nc] = A @ W, fused el/er. flags: 1 bias, 2 lrelu,
// 4 el/er, 8 fp32 C, 16 hi plane, 32 lo plane.
__global__ __launch_bounds__(256) void gemm_mfma(
    const short* __restrict__ Ahi, const short* __restrict__ Alo,
    const short* __restrict__ Bth, const short* __restrict__ Btl,
    const float* __restrict__ bias,
    float* __restrict__ Cf, short* __restrict__ Chi, short* __restrict__ Clo,
    float* __restrict__ el, float* __restrict__ er,
    const float* __restrict__ al, const float* __restrict__ ar,
    int M, int Nc, int flags)
{
    __shared__ short Ah[BM * LSTR], Al_[BM * LSTR];
    __shared__ short Bh[BN * LSTR], Bl_[BN * LSTR];

    int tid = threadIdx.x, lane = tid & 63, wave = tid >> 6;
    int l15 = lane & 15, q = lane >> 4;
    int rowBase = blockIdx.y * BM, colBase = blockIdx.x * BN;

    float4v acc[2][8];
    #pragma unroll
    for (int mt = 0; mt < 2; ++mt)
        #pragma unroll
        for (int nt = 0; nt < 8; ++nt)
            acc[mt][nt] = (float4v){0.f, 0.f, 0.f, 0.f};

    for (int k0 = 0; k0 < 128; k0 += BK) {
        #pragma unroll
        for (int s = 0; s < 2; ++s) {
            int c = tid + s * 256;
            int r = c >> 2, kq = (c & 3) * 8;
            int gr = rowBase + r;
            short8 vh = zero8(), vl = zero8();
            if (gr < M) {
                vh = *(const short8*)(Ahi + (size_t)gr * 128 + k0 + kq);
                vl = *(const short8*)(Alo + (size_t)gr * 128 + k0 + kq);
            }
            *(short8*)&Ah[r * LSTR + kq]  = vh;
            *(short8*)&Al_[r * LSTR + kq] = vl;
            int gc = colBase + r;
            short8 wh = zero8(), wl = zero8();
            if (gc < Nc) {
                wh = *(const short8*)(Bth + (size_t)gc * 128 + k0 + kq);
                wl = *(const short8*)(Btl + (size_t)gc * 128 + k0 + kq);
            }
            *(short8*)&Bh[r * LSTR + kq]  = wh;
            *(short8*)&Bl_[r * LSTR + kq] = wl;
        }
        __syncthreads();

        short8 aH[2], aL2[2];
        #pragma unroll
        for (int mt = 0; mt < 2; ++mt) {
            int off = (wave * 32 + mt * 16 + l15) * LSTR + q * 8;
            aH[mt]  = *(short8*)&Ah[off];
            aL2[mt] = *(short8*)&Al_[off];
        }
        #pragma unroll
        for (int nt = 0; nt < 8; ++nt) {
            int off = (nt * 16 + l15) * LSTR + q * 8;
            short8 bH = *(short8*)&Bh[off];
            short8 bL = *(short8*)&Bl_[off];
            #pragma unroll
            for (int mt = 0; mt < 2; ++mt) {
                acc[mt][nt] = __builtin_amdgcn_mfma_f32_16x16x32_bf16(aH[mt], bH, acc[mt][nt], 0, 0, 0);
                acc[mt][nt] = __builtin_amdgcn_mfma_f32_16x16x32_bf16(aH[mt], bL, acc[mt][nt], 0, 0, 0);
                acc[mt][nt] = __builtin_amdgcn_mfma_f32_16x16x32_bf16(aL2[mt], bH, acc[mt][nt], 0, 0, 0);
            }
        }
        __syncthreads();
    }

    if (flags & 4) {
        const float* alh = al + colBase;
        const float* arh = ar + colBase;
        float pel[2][4] = {}, per_[2][4] = {};
        #pragma unroll
        for (int nt = 0; nt < 8; ++nt) {
            float av = alh[nt * 16 + l15];
            float rv = arh[nt * 16 + l15];
            #pragma unroll
            for (int mt = 0; mt < 2; ++mt)
                #pragma unroll
                for (int i = 0; i < 4; ++i) {
                    pel[mt][i]  += acc[mt][nt][i] * av;
                    per_[mt][i] += acc[mt][nt][i] * rv;
                }
        }
        #pragma unroll
        for (int mask = 1; mask < 16; mask <<= 1)
            #pragma unroll
            for (int mt = 0; mt < 2; ++mt)
                #pragma unroll
                for (int i = 0; i < 4; ++i) {
                    pel[mt][i]  += __shfl_xor(pel[mt][i], mask);
                    per_[mt][i] += __shfl_xor(per_[mt][i], mask);
                }
        if (l15 == 0) {
            #pragma unroll
            for (int mt = 0; mt < 2; ++mt)
                #pragma unroll
                for (int i = 0; i < 4; ++i) {
                    int r = rowBase + wave * 32 + mt * 16 + q * 4 + i;
                    if (r < M) {
                        el[r * 3 + blockIdx.x] = pel[mt][i];
                        er[r * 3 + blockIdx.x] = per_[mt][i];
                    }
                }
        }
    }

    #pragma unroll
    for (int mt = 0; mt < 2; ++mt) {
        #pragma unroll
        for (int nt = 0; nt < 8; ++nt) {
            int c = colBase + nt * 16 + l15;
            if (c >= Nc) continue;
            float bv = (flags & 1) ? bias[c] : 0.f;
            #pragma unroll
            for (int i = 0; i < 4; ++i) {
                int r = rowBase + wave * 32 + mt * 16 + q * 4 + i;
                if (r >= M) continue;
                float v = acc[mt][nt][i] + bv;
                if (flags & 2) v = (v < 0.f) ? 0.01f * v : v;
                size_t idx = (size_t)r * Nc + c;
                if (flags & 8)  Cf[idx] = v;
                if (flags & 16) {
                    short hh = f2bf(v);
                    Chi[idx] = hh;
                    if (flags & 32) Clo[idx] = f2bf(v - bf2f(hh));
                }
            }
        }
    }
}

// ---------------------------------------------------------------------------
// Fused MLP head: 4x (128->128, bias, lrelu) + (128->6, bias) in one kernel.
__global__ __launch_bounds__(256) void mlp_fused(
    const short* __restrict__ Ph, const short* __restrict__ Pl,
    const short* __restrict__ w1h, const short* __restrict__ w1l,
    const short* __restrict__ w2h, const short* __restrict__ w2l,
    const short* __restrict__ w3h, const short* __restrict__ w3l,
    const short* __restrict__ w4h, const short* __restrict__ w4l,
    const short* __restrict__ w5h, const short* __restrict__ w5l,
    const float* __restrict__ b1, const float* __restrict__ b2,
    const float* __restrict__ b3, const float* __restrict__ b4,
    const float* __restrict__ b5,
    float* __restrict__ out, int M)
{
    __shared__ short AH[MROWS * MSTR], AL[MROWS * MSTR];
    __shared__ short WH[128 * LSTR], WL[128 * LSTR];

    int tid = threadIdx.x, lane = tid & 63, wave = tid >> 6;
    int l15 = lane & 15, q = lane >> 4;
    int rowBase = blockIdx.x * MROWS;

    #pragma unroll
    for (int s = 0; s < 4; ++s) {
        int idx = tid + s * 256;
        int r = idx >> 4, kq = (idx & 15) * 8;
        int gr = rowBase + r;
        short8 vh = zero8(), vl = zero8();
        if (gr < M) {
            vh = *(const short8*)(Ph + (size_t)gr * 128 + kq);
            vl = *(const short8*)(Pl + (size_t)gr * 128 + kq);
        }
        *(short8*)&AH[r * MSTR + kq] = vh;
        *(short8*)&AL[r * MSTR + kq] = vl;
    }

    const short* Whs[4] = {w1h, w2h, w3h, w4h};
    const short* Wls[4] = {w1l, w2l, w3l, w4l};
    const float* Bss[4] = {b1, b2, b3, b4};

    #pragma unroll
    for (int L = 0; L < 4; ++L) {
        float4v acc[8];
        #pragma unroll
        for (int nt = 0; nt < 8; ++nt)
            acc[nt] = (float4v){0.f, 0.f, 0.f, 0.f};

        for (int k0 = 0; k0 < 128; k0 += BK) {
            #pragma unroll
            for (int s = 0; s < 4; ++s) {
                int idx = tid + s * 256;
                int plane = idx >> 9, rem = idx & 511;
                int c = rem >> 2, kq = (rem & 3) * 8;
                short8 v = *(const short8*)((plane ? Wls[L] : Whs[L]) +
                                            (size_t)c * 128 + k0 + kq);
                *(short8*)&((plane ? WL : WH)[c * LSTR + kq]) = v;
            }
            __syncthreads();
            int offa = (wave * 16 + l15) * MSTR + k0 + q * 8;
            short8 aH  = *(short8*)&AH[offa];
            short8 aL2 = *(short8*)&AL[offa];
            #pragma unroll
            for (int nt = 0; nt < 8; ++nt) {
                int off = (nt * 16 + l15) * LSTR + q * 8;
                short8 bH = *(short8*)&WH[off];
                short8 bL = *(short8*)&WL[off];
                acc[nt] = __builtin_amdgcn_mfma_f32_16x16x32_bf16(aH, bH, acc[nt], 0, 0, 0);
                acc[nt] = __builtin_amdgcn_mfma_f32_16x16x32_bf16(aH, bL, acc[nt], 0, 0, 0);
                acc[nt] = __builtin_amdgcn_mfma_f32_16x16x32_bf16(aL2, bH, acc[nt], 0, 0, 0);
            }
            __syncthreads();
        }
        #pragma unroll
        for (int nt = 0; nt < 8; ++nt) {
            int c = nt * 16 + l15;
            float bv = Bss[L][c];
            #pragma unroll
            for (int i = 0; i < 4; ++i) {
                int r = wave * 16 + q * 4 + i;
                float v = acc[nt][i] + bv;
                v = (v < 0.f) ? 0.01f * v : v;
                short hh = f2bf(v);
                AH[r * MSTR + c] = hh;
                AL[r * MSTR + c] = f2bf(v - bf2f(hh));
            }
        }
        __syncthreads();
    }

    float4v acc5 = (float4v){0.f, 0.f, 0.f, 0.f};
    for (int k0 = 0; k0 < 128; k0 += BK) {
        if (tid < 128) {
            int plane = tid >> 6, rem = tid & 63;
            int c = rem >> 2, kq = (rem & 3) * 8;
            short8 v = zero8();
            if (c < 6)
                v = *(const short8*)((plane ? w5l : w5h) + (size_t)c * 128 + k0 + kq);
            *(short8*)&((plane ? WL : WH)[c * LSTR + kq]) = v;
        }
        __syncthreads();
        int offa = (wave * 16 + l15) * MSTR + k0 + q * 8;
        short8 aH  = *(short8*)&AH[offa];
        short8 aL2 = *(short8*)&AL[offa];
        int offb = l15 * LSTR + q * 8;
        short8 bH = *(short8*)&WH[offb];
        short8 bL = *(short8*)&WL[offb];
        acc5 = __builtin_amdgcn_mfma_f32_16x16x32_bf16(aH, bH, acc5, 0, 0, 0);
        acc5 = __builtin_amdgcn_mfma_f32_16x16x32_bf16(aH, bL, acc5, 0, 0, 0);
        acc5 = __builtin_amdgcn_mfma_f32_16x16x32_bf16(aL2, bH, acc5, 0, 0, 0);
        __syncthreads();
    }
    if (l15 < 6) {
        float bv = b5[l15];
        #pragma unroll
        for (int i = 0; i < 4; ++i) {
            int r = rowBase + wave * 16 + q * 4 + i;
            if (r < M) out[(size_t)r * 6 + l15] = acc5[i] + bv;
        }
    }
}

// ---------------------------------------------------------------------------
// CSR build (hist lives in prep_kernel)
__global__ __launch_bounds__(1024) void scan_block(const int* __restrict__ cnt,
                                                   int* __restrict__ off,
                                                   int* __restrict__ bsum, int n)
{
    __shared__ int tmp[1024];
    int tid = threadIdx.x;
    int i = blockIdx.x * 1024 + tid;
    int v = (i < n) ? cnt[i] : 0;
    tmp[tid] = v;
    __syncthreads();
    for (int s = 1; s < 1024; s <<= 1) {
        int t = (tid >= s) ? tmp[tid - s] : 0;
        __syncthreads();
        tmp[tid] += t;
        __syncthreads();
    }
    if (i < n) off[i] = tmp[tid] - v;
    if (tid == 1023) bsum[blockIdx.x] = tmp[1023];
}

__global__ void scan_add2(int* __restrict__ off, const int* __restrict__ bsum,
                          int n, int nb)
{
    __shared__ int pre[64];
    int tid = threadIdx.x;
    if (tid < 64) {
        int v = (tid < nb) ? bsum[tid] : 0;
        #pragma unroll
        for (int s = 1; s < 64; s <<= 1) {
            int t = __shfl_up(v, s);
            if (tid >= s) v += t;
        }
        pre[tid] = v;
    }
    __syncthreads();
    int i = blockIdx.x * blockDim.x + tid;
    if (i < n) {
        int chunk = i >> 10;
        off[i] += chunk ? pre[chunk - 1] : 0;
    }
    if (i == 0) off[n] = pre[nb - 1];
}

__global__ void scatter_kernel(const int* __restrict__ src, const int* __restrict__ dst,
                               const int* __restrict__ off, int* __restrict__ cnt,
                               int* __restrict__ csrc, int E)
{
    int e = blockIdx.x * blockDim.x + threadIdx.x;
    if (e < E) {
        int d = dst[e];
        int p = atomicSub(&cnt[d], 1) - 1;
        csrc[off[d] + p] = src[e];
    }
}

// ---------------------------------------------------------------------------
// Fused edge-softmax + weighted gather + bias + lrelu + head-mean.
// Block per node, 192 threads = 3 waves; wave w == head w, lane l owns
// feature pair (2l, 2l+1). Wave-uniform 256 B row gather (R9-proven).
__global__ __launch_bounds__(192) void agg_kernel(
    const short* __restrict__ h, const float* __restrict__ el,
    const float* __restrict__ er, const int* __restrict__ off,
    const int* __restrict__ csrc, const float* __restrict__ bias,
    short* __restrict__ outH, short* __restrict__ outL, int N)
{
    int n = blockIdx.x;
    int tid = threadIdx.x;         // 0..191
    int head = tid >> 6;           // 0..2 == wave index
    int l = tid & 63;
    int beg = off[n], end = off[n + 1];
    int deg = end - beg;

    __shared__ int   ssrc[64];
    __shared__ float sw[3][64];    // wave-private rows
    __shared__ float sm[384];

    int fbase = head * 128 + 2 * l;
    float erv = er[n * 3 + head];
    float ax = 0.f, ay = 0.f, den = 0.f, m_run = -1e30f;

    for (int base = 0; base < deg; base += 64) {
        int cnt = min(64, deg - base);
        if (tid < cnt) ssrc[tid] = csrc[beg + base + tid];
        __syncthreads();
        float e = -1e30f;
        if (l < cnt) {
            float t = el[ssrc[l] * 3 + head] + erv;
            e = (t < 0.f) ? 0.2f * t : t;
        }
        float mc = e;
        #pragma unroll
        for (int msk = 1; msk < 64; msk <<= 1) mc = fmaxf(mc, __shfl_xor(mc, msk));
        float m_new = fmaxf(m_run, mc);
        float scale = __expf(m_run - m_new);
        ax *= scale; ay *= scale; den *= scale;
        float w = (l < cnt) ? __expf(e - m_new) : 0.f;
        float wsum = w;
        #pragma unroll
        for (int msk = 1; msk < 64; msk <<= 1) wsum += __shfl_xor(wsum, msk);
        den += wsum;
        sw[head][l] = w;
        m_run = m_new;
        #pragma unroll 4
        for (int qq = 0; qq < cnt; ++qq) {
            int s = ssrc[qq];
            float w2 = sw[head][qq];
            unsigned v = *(const unsigned*)(h + (size_t)s * 384 + fbase);
            union { unsigned u; float f; } f0, f1;
            f0.u = v << 16; f1.u = v & 0xffff0000u;
            ax += w2 * f0.f;
            ay += w2 * f1.f;
        }
        __syncthreads();
    }
    float r = 1.f / (den + 1e-9f);
    if (deg == 0) r = 0.f;
    float2 bv = *(const float2*)(bias + fbase);
    float vx = ax * r + bv.x; vx = (vx < 0.f) ? 0.01f * vx : vx;
    float vy = ay * r + bv.y; vy = (vy < 0.f) ? 0.01f * vy : vy;
    sm[fbase]     = vx;
    sm[fbase + 1] = vy;
    __syncthreads();
    if (tid < 64) {
        int f0i = tid * 2, f1i = f0i + 1;
        float mx = (sm[f0i] + sm[128 + f0i] + sm[256 + f0i]) * (1.0f / 3.0f);
        float my = (sm[f1i] + sm[128 + f1i] + sm[256 + f1i]) * (1.0f / 3.0f);
        short hx = f2bf(mx), lx = f2bf(mx - bf2f(hx));
        short hy = f2bf(my), ly = f2bf(my - bf2f(hy));
        unsigned ph = (unsigned)(unsigned short)hx | ((unsigned)(unsigned short)hy << 16);
        unsigned pl = (unsigned)(unsigned short)lx | ((unsigned)(unsigned short)ly << 16);
        *(unsigned*)(outH + (size_t)n * 128 + f0i) = ph;
        *(unsigned*)(outL + (size_t)n * 128 + f0i) = pl;
    }
}

// ---------------------------------------------------------------------------
extern "C" void kernel_launch(void* const* d_in, const int* in_sizes, int n_in,
                              void* d_out, int out_size, void* d_ws, size_t ws_size,
                              hipStream_t stream)
{
    const float* in_feat = (const float*)d_in[0];
    const int*   src     = (const int*)d_in[1];
    const int*   dst     = (const int*)d_in[2];
    const float* W1  = (const float*)d_in[3];
    const float* al1 = (const float*)d_in[4];
    const float* ar1 = (const float*)d_in[5];
    const float* b1  = (const float*)d_in[6];
    const float* W2  = (const float*)d_in[7];
    const float* al2 = (const float*)d_in[8];
    const float* ar2 = (const float*)d_in[9];
    const float* b2  = (const float*)d_in[10];
    const float* lw1 = (const float*)d_in[11];
    const float* lb1 = (const float*)d_in[12];
    const float* lw2 = (const float*)d_in[13];
    const float* lb2 = (const float*)d_in[14];
    const float* lw3 = (const float*)d_in[15];
    const float* lb3 = (const float*)d_in[16];
    const float* lw4 = (const float*)d_in[17];
    const float* lb4 = (const float*)d_in[18];
    const float* lw5 = (const float*)d_in[19];
    const float* lb5 = (const float*)d_in[20];

    const int N = in_sizes[0] / 128;   // 50000
    const int E = in_sizes[1];         // 800000

    size_t o = 0;
    auto alloc = [&](size_t bytes) { size_t p = o; o = (o + bytes + 255) & ~(size_t)255; return p; };
    char* ws = (char*)d_ws;
    short* P1h = (short*)(ws + alloc((size_t)N * 128 * 2));
    short* P1l = (short*)(ws + alloc((size_t)N * 128 * 2));
    short* P2h = (short*)(ws + alloc((size_t)N * 128 * 2));
    short* P2l = (short*)(ws + alloc((size_t)N * 128 * 2));
    short* AbH = (short*)(ws + alloc((size_t)N * 384 * 2));   // GAT gemm out, hi, node-major
    float* el  = (float*)(ws + alloc((size_t)N * 3 * 4));
    float* er  = (float*)(ws + alloc((size_t)N * 3 * 4));
    int*   cnt  = (int*)(ws + alloc((size_t)N * 4));
    int*   off  = (int*)(ws + alloc((size_t)(N + 1) * 4));
    int*   bsum = (int*)(ws + alloc((size_t)4096));
    int*   csrc = (int*)(ws + alloc((size_t)E * 4));
    short* w1th = (short*)(ws + alloc((size_t)384 * 128 * 2));
    short* w1tl = (short*)(ws + alloc((size_t)384 * 128 * 2));
    short* w2th = (short*)(ws + alloc((size_t)384 * 128 * 2));
    short* w2tl = (short*)(ws + alloc((size_t)384 * 128 * 2));
    short* l1th = (short*)(ws + alloc((size_t)128 * 128 * 2));
    short* l1tl = (short*)(ws + alloc((size_t)128 * 128 * 2));
    short* l2th = (short*)(ws + alloc((size_t)128 * 128 * 2));
    short* l2tl = (short*)(ws + alloc((size_t)128 * 128 * 2));
    short* l3th = (short*)(ws + alloc((size_t)128 * 128 * 2));
    short* l3tl = (short*)(ws + alloc((size_t)128 * 128 * 2));
    short* l4th = (short*)(ws + alloc((size_t)128 * 128 * 2));
    short* l4tl = (short*)(ws + alloc((size_t)128 * 128 * 2));
    short* l5th = (short*)(ws + alloc((size_t)6 * 128 * 2));
    short* l5tl = (short*)(ws + alloc((size_t)6 * 128 * 2));
    (void)ws_size;

    float* out = (float*)d_out;

    // ---- fused prep: conv_split + weight transpose + hist (one launch)
    hipMemsetAsync(cnt, 0, (size_t)N * 4, stream);
    int n4 = N * 128 / 4;
    int cb = (n4 + 255) / 256;
    int wb = (164608 + 255) / 256;
    int hb = (E + 255) / 256;
    prep_kernel<<<cb + wb + hb, 256, 0, stream>>>(
        in_feat, P1h, P1l, n4, cb, wb, dst, cnt, E,
        W1, W2, lw1, lw2, lw3, lw4, lw5,
        w1th, w1tl, w2th, w2tl, l1th, l1tl, l2th, l2tl,
        l3th, l3tl, l4th, l4tl, l5th, l5tl);

    // ---- CSR scan + scatter
    int nb = (N + 1023) / 1024;
    scan_block<<<nb, 1024, 0, stream>>>(cnt, off, bsum, N);
    scan_add2<<<(N + 255) / 256, 256, 0, stream>>>(off, bsum, N, nb);
    scatter_kernel<<<(E + 255) / 256, 256, 0, stream>>>(src, dst, off, cnt, csrc, E);

    int RB = (N + BM - 1) / BM;
    auto gemm = [&](const short* ah, const short* alo, const short* bth, const short* btl,
                    const float* bias, float* cf, short* chi, short* clo,
                    float* elp, float* erp, const float* alp, const float* arp,
                    int Nc, int flags) {
        dim3 grid((Nc + BN - 1) / BN, RB);
        gemm_mfma<<<grid, 256, 0, stream>>>(ah, alo, bth, btl, bias, cf, chi, clo,
                                            elp, erp, alp, arp, N, Nc, flags);
    };

    // ---- GAT layer 1
    gemm(P1h, P1l, w1th, w1tl, nullptr, nullptr, AbH, nullptr, el, er, al1, ar1, 384, 4 | 16);
    agg_kernel<<<N, 192, 0, stream>>>(AbH, el, er, off, csrc, b1, P2h, P2l, N);

    // ---- GAT layer 2
    gemm(P2h, P2l, w2th, w2tl, nullptr, nullptr, AbH, nullptr, el, er, al2, ar2, 384, 4 | 16);
    agg_kernel<<<N, 192, 0, stream>>>(AbH, el, er, off, csrc, b2, P1h, P1l, N);

    // ---- MLP head (fused lin1..lin5, 64-node blocks)
    int RBM = (N + MROWS - 1) / MROWS;
    mlp_fused<<<RBM, 256, 0, stream>>>(P1h, P1l,
                                       l1th, l1tl, l2th, l2tl, l3th, l3tl,
                                       l4th, l4tl, l5th, l5tl,
                                       lb1, lb2, lb3, lb4, lb5, out, N);
}